// Round 3
// baseline (264.353 us; speedup 1.0000x reference)
//
#include <hip/hip_runtime.h>
#include <math.h>

// Problem constants: B=2, L=1024, D=512, H=8, h=64, K=H=8, EPS=1e-5
// R3: mega-kernel as R2, but PLAIN launch (graph-capturable) + manual grid
// barrier (device-scope atomics, sense-free: one counter slot per sync point,
// zeroed by hipMemsetAsync before launch).  Co-residency guaranteed: 256
// blocks <= 256 CUs, LDS 55552 B <= 160 KiB, __launch_bounds__(256,1).
// Phase layout identical to R2 (bit-identical math to the R1-verified split
// kernels):
//   P0 prep -> P1 qkv -> P2 conv+gate (kts/vts persist in LDS) -> P3 amat
//   -> P3.5 AP-reduce -> P4 ctxt -> P5 out

typedef __attribute__((ext_vector_type(8))) short short8;
typedef __attribute__((ext_vector_type(4))) float floatx4;

__device__ __forceinline__ unsigned short f2bf(float f) {
    unsigned int u = __float_as_uint(f);
    unsigned int r = (u + 0x7FFFu + ((u >> 16) & 1u)) >> 16;   // RNE
    return (unsigned short)r;
}

// Grid barrier: slot must be a fresh zeroed counter per sync point.
__device__ __forceinline__ void gsync(unsigned int* cnt, unsigned target) {
    __syncthreads();
    if (threadIdx.x == 0) {
        __threadfence();                 // agent-scope release (L2 writeback)
        __hip_atomic_fetch_add(cnt, 1u, __ATOMIC_RELAXED,
                               __HIP_MEMORY_SCOPE_AGENT);
        while (__hip_atomic_load(cnt, __ATOMIC_RELAXED,
                                 __HIP_MEMORY_SCOPE_AGENT) < target) {
            __builtin_amdgcn_s_sleep(2);
        }
        __threadfence();                 // agent-scope acquire (cache inv)
    }
    __syncthreads();
}

__global__ __launch_bounds__(256, 1) void k_mega(
    const float* __restrict__ x, const float* __restrict__ sb,
    const float* __restrict__ wq, const float* __restrict__ wk,
    const float* __restrict__ wv, const float* __restrict__ wo,
    const float* __restrict__ wgw,
    const float* __restrict__ bq, const float* __restrict__ bk,
    const float* __restrict__ bv, const float* __restrict__ bo,
    const float* __restrict__ wgbias,
    unsigned short* __restrict__ XB, unsigned short* __restrict__ WT,
    unsigned short* __restrict__ WOT, unsigned short* __restrict__ WGB,
    float* __restrict__ Qb, unsigned short* __restrict__ UB2,
    float* __restrict__ GL, float* __restrict__ AP,
    float* __restrict__ AF, unsigned short* __restrict__ UB,
    float* __restrict__ out,
    unsigned int* __restrict__ CNT)
{
    const int blk = blockIdx.x;
    const int tid = threadIdx.x;
    const int lane = tid & 63, wave = tid >> 6;
    const int qd = lane >> 4, ln = lane & 15;
    const int tx = tid & 15, ty = tid >> 4;

    __shared__ __align__(16) unsigned char arena[55552];

    // =====================================================================
    // P0: prep.  Each block: 2 castx units, 1 packw unit; blk 0 also wg.
    // =====================================================================
    {
        float (*sf)[65] = (float(*)[65])arena;
        const float4* x4 = (const float4*)x;
        #pragma unroll
        for (int u = 0; u < 2; ++u) {
            int gid = (blk + u*256) * 256 + tid;
            float4 a = x4[gid*2], b = x4[gid*2+1];
            uint4 o;
            o.x = f2bf(a.x) | ((unsigned)f2bf(a.y) << 16);
            o.y = f2bf(a.z) | ((unsigned)f2bf(a.w) << 16);
            o.z = f2bf(b.x) | ((unsigned)f2bf(b.y) << 16);
            o.w = f2bf(b.z) | ((unsigned)f2bf(b.w) << 16);
            ((uint4*)XB)[gid] = o;
        }
        {
            const int t = blk;
            const float* src; unsigned short* dst; int n0p, c0, k0p;
            if (t < 192) {
                int nt = t >> 3, kt = t & 7;
                n0p = nt * 64; k0p = kt * 64;
                int z = n0p >> 9; c0 = n0p & 511;
                src = (z == 0) ? wq : (z == 1) ? wk : wv;
                dst = WT;
            } else {
                int u = t - 192; int nt = u >> 3, kt = u & 7;
                n0p = nt * 64; c0 = n0p; k0p = kt * 64;
                src = wo; dst = WOT;
            }
            const int rr = tid >> 4, c4 = tid & 15;
            #pragma unroll
            for (int g = 0; g < 4; ++g) {
                int r = g*16 + rr;
                float4 v = *(const float4*)&src[(size_t)(k0p + r)*512 + c0 + c4*4];
                sf[r][c4*4+0]=v.x; sf[r][c4*4+1]=v.y; sf[r][c4*4+2]=v.z; sf[r][c4*4+3]=v.w;
            }
            __syncthreads();
            #pragma unroll
            for (int g = 0; g < 4; ++g) {
                int c = g*16 + rr;
                int kk = c4*4;
                ushort4 o;
                o.x = f2bf(sf[kk+0][c]); o.y = f2bf(sf[kk+1][c]);
                o.z = f2bf(sf[kk+2][c]); o.w = f2bf(sf[kk+3][c]);
                *(ushort4*)&dst[(size_t)(n0p + c)*512 + k0p + kk] = o;
            }
        }
        if (blk == 0) {
            const float4* wg4 = (const float4*)wgw;
            for (int i = tid; i < 512; i += 256) {
                float4 a = wg4[i*2], b = wg4[i*2+1];
                uint4 o;
                o.x = f2bf(a.x) | ((unsigned)f2bf(a.y) << 16);
                o.y = f2bf(a.z) | ((unsigned)f2bf(a.w) << 16);
                o.z = f2bf(b.x) | ((unsigned)f2bf(b.y) << 16);
                o.w = f2bf(b.z) | ((unsigned)f2bf(b.w) << 16);
                ((uint4*)WGB)[i] = o;
            }
        }
    }
    gsync(CNT + 0, 256);

    // =====================================================================
    // P1: QKV projection.  384 tiles (128m x 64n), blocks 0-127 do two.
    // =====================================================================
    {
        unsigned short* As = (unsigned short*)arena;            // 128*72
        unsigned short* Bs = (unsigned short*)(arena + 18432);  // 64*72
        const int wm = wave * 32;
        const uint4* Ag = (const uint4*)XB;
        const uint4* Bg = (const uint4*)WT;
        for (int t = blk; t < 384; t += 256) {
            const int m0 = (t / 24) * 128;
            const int n0 = (t % 24) * 64;

            floatx4 acc[2][4];
            #pragma unroll
            for (int i = 0; i < 2; ++i)
                #pragma unroll
                for (int j = 0; j < 4; ++j)
                    acc[i][j] = (floatx4){0.f, 0.f, 0.f, 0.f};

            for (int k0 = 0; k0 < 512; k0 += 64) {
                #pragma unroll
                for (int s = 0; s < 4; ++s) {
                    int idx = s*256 + tid;
                    int r = idx >> 3, cp = idx & 7;
                    uint4 va = Ag[(size_t)(m0 + r)*64 + (k0 >> 3) + cp];
                    *(uint4*)&As[r*72 + cp*8] = va;
                }
                #pragma unroll
                for (int s = 0; s < 2; ++s) {
                    int idx = s*256 + tid;
                    int r = idx >> 3, cp = idx & 7;
                    uint4 vb = Bg[(size_t)(n0 + r)*64 + (k0 >> 3) + cp];
                    *(uint4*)&Bs[r*72 + cp*8] = vb;
                }
                __syncthreads();
                short8 af0[2], af1[2], bf0[4], bf1[4];
                #pragma unroll
                for (int i = 0; i < 2; ++i) {
                    af0[i] = *(const short8*)&As[(wm + i*16 + ln)*72 + qd*8];
                    af1[i] = *(const short8*)&As[(wm + i*16 + ln)*72 + 32 + qd*8];
                }
                #pragma unroll
                for (int i = 0; i < 4; ++i) {
                    bf0[i] = *(const short8*)&Bs[(i*16 + ln)*72 + qd*8];
                    bf1[i] = *(const short8*)&Bs[(i*16 + ln)*72 + 32 + qd*8];
                }
                #pragma unroll
                for (int mi = 0; mi < 2; ++mi)
                    #pragma unroll
                    for (int ni = 0; ni < 4; ++ni) {
                        acc[mi][ni] = __builtin_amdgcn_mfma_f32_16x16x32_bf16(
                            af0[mi], bf0[ni], acc[mi][ni], 0, 0, 0);
                        acc[mi][ni] = __builtin_amdgcn_mfma_f32_16x16x32_bf16(
                            af1[mi], bf1[ni], acc[mi][ni], 0, 0, 0);
                    }
                __syncthreads();
            }

            const int z = n0 >> 9;
            if (z == 0) {
                #pragma unroll
                for (int mi = 0; mi < 2; ++mi) {
                    #pragma unroll
                    for (int ni = 0; ni < 4; ++ni) {
                        int c = (n0 + ni*16 + ln) & 511;
                        int head = c >> 6, dd = c & 63;
                        float bb = bq[c];
                        #pragma unroll
                        for (int reg = 0; reg < 4; ++reg) {
                            int row = m0 + wm + mi*16 + qd*4 + reg;
                            int b = row >> 10, l = row & 1023;
                            Qb[(size_t)((b*8 + head)*1024 + l)*64 + dd] =
                                acc[mi][ni][reg] + bb;
                        }
                    }
                }
            } else {
                const float scale = (z == 1) ? 0.125f : 1.0f;
                const float* bias = (z == 1) ? bk : bv;
                unsigned short* dst = UB2 + (size_t)(z-1) * 16 * 64 * 1024;
                #pragma unroll
                for (int mi = 0; mi < 2; ++mi) {
                    #pragma unroll
                    for (int ni = 0; ni < 4; ++ni) {
                        int c = (n0 + ni*16 + ln) & 511;
                        int head = c >> 6, dd = c & 63;
                        float bb = bias[c];
                        int row0 = m0 + wm + mi*16 + qd*4;
                        int b = row0 >> 10, l0 = row0 & 1023;
                        ushort4 o;
                        o.x = f2bf((acc[mi][ni][0] + bb) * scale);
                        o.y = f2bf((acc[mi][ni][1] + bb) * scale);
                        o.z = f2bf((acc[mi][ni][2] + bb) * scale);
                        o.w = f2bf((acc[mi][ni][3] + bb) * scale);
                        *(ushort4*)&dst[((size_t)((b*8 + head)*64) + dd)*1024 + l0] = o;
                    }
                }
            }
        }
    }
    gsync(CNT + 1, 256);

    // =====================================================================
    // P2: conv (k AND v) + gate.  block (bh = blk&15, it = blk>>4).
    // Conv outputs stay in LDS (kts/vts) for P3; only gl goes to global.
    // =====================================================================
    {
        float (*kts)[68] = (float(*)[68])arena;
        float (*vts)[68] = (float(*)[68])(arena + 17408);
        unsigned short* revf = (unsigned short*)(arena + 34816);
        unsigned short* Bk = (unsigned short*)(arena + 37120);
        unsigned short* Bv = (unsigned short*)(arena + 46336);
        const int bh = blk & 15, h = bh & 7;
        const int it = blk >> 4, t0 = it * 64;

        for (int i = tid; i < 1152; i += 256) {
            int d = 1087 - i;
            revf[i] = (d >= 0 && d < 1024) ? f2bf(sb[d*8 + h]) : (unsigned short)0;
        }

        const uint4* Bg = (const uint4*)UB2;
        const size_t bk_base = (size_t)bh * 8192;
        const size_t bv_base = (size_t)(16 + bh) * 8192;

        floatx4 acck[4], accv[4];
        #pragma unroll
        for (int i = 0; i < 4; ++i) {
            acck[i] = (floatx4){0.f,0.f,0.f,0.f};
            accv[i] = (floatx4){0.f,0.f,0.f,0.f};
        }

        const int kend = t0 + 64;
        const int arow = 1087 - t0 - (wave*16 + ln);
        for (int k0 = 0; k0 < kend; k0 += 64) {
            #pragma unroll
            for (int s = 0; s < 2; ++s) {
                int idx = s*256 + tid;
                int r = idx >> 3, cp = idx & 7;
                *(uint4*)&Bk[r*72 + cp*8] = Bg[bk_base + (size_t)r*128 + (k0 >> 3) + cp];
                *(uint4*)&Bv[r*72 + cp*8] = Bg[bv_base + (size_t)r*128 + (k0 >> 3) + cp];
            }
            __syncthreads();                   // also covers revf on first iter
            const int ab = arow + k0 + qd*8;
            short8 a0, a1;
            #pragma unroll
            for (int j = 0; j < 8; ++j) {
                a0[j] = (short)revf[ab + j];
                a1[j] = (short)revf[ab + 32 + j];
            }
            #pragma unroll
            for (int ni = 0; ni < 4; ++ni) {
                short8 kb0 = *(const short8*)&Bk[(ni*16 + ln)*72 + qd*8];
                short8 kb1 = *(const short8*)&Bk[(ni*16 + ln)*72 + 32 + qd*8];
                short8 vb0 = *(const short8*)&Bv[(ni*16 + ln)*72 + qd*8];
                short8 vb1 = *(const short8*)&Bv[(ni*16 + ln)*72 + 32 + qd*8];
                acck[ni] = __builtin_amdgcn_mfma_f32_16x16x32_bf16(a0, kb0, acck[ni], 0, 0, 0);
                acck[ni] = __builtin_amdgcn_mfma_f32_16x16x32_bf16(a1, kb1, acck[ni], 0, 0, 0);
                accv[ni] = __builtin_amdgcn_mfma_f32_16x16x32_bf16(a0, vb0, accv[ni], 0, 0, 0);
                accv[ni] = __builtin_amdgcn_mfma_f32_16x16x32_bf16(a1, vb1, accv[ni], 0, 0, 0);
            }
            __syncthreads();
        }

        // epilogue: conv tiles -> LDS (persist), KCb bf16 -> Bk, Wgb -> Bv
        #pragma unroll
        for (int ni = 0; ni < 4; ++ni)
            #pragma unroll
            for (int reg = 0; reg < 4; ++reg) {
                int row = wave*16 + qd*4 + reg;
                kts[row][ni*16 + ln] = acck[ni][reg];
                vts[row][ni*16 + ln] = accv[ni][reg];
                Bk[row*72 + ni*16 + ln] = f2bf(acck[ni][reg]);
            }
        {
            const uint4* Wg = (const uint4*)WGB;
            #pragma unroll
            for (int s = 0; s < 2; ++s) {
                int idx = s*256 + tid;
                int r = idx >> 3, cp = idx & 7;
                *(uint4*)&Bv[r*72 + cp*8] = Wg[r*8 + cp];
            }
        }
        __syncthreads();

        floatx4 T[4];
        #pragma unroll
        for (int mt = 0; mt < 4; ++mt) T[mt] = (floatx4){0.f,0.f,0.f,0.f};
        #pragma unroll
        for (int k0g = 0; k0g < 64; k0g += 32) {
            short8 a = *(const short8*)&Bk[(wave*16 + ln)*72 + k0g + qd*8];
            #pragma unroll
            for (int mt = 0; mt < 4; ++mt) {
                short8 b = *(const short8*)&Bv[(mt*16 + ln)*72 + k0g + qd*8];
                T[mt] = __builtin_amdgcn_mfma_f32_16x16x32_bf16(a, b, T[mt], 0, 0, 0);
            }
        }

        float part[4] = {0.f, 0.f, 0.f, 0.f};
        #pragma unroll
        for (int mt = 0; mt < 4; ++mt)
            #pragma unroll
            for (int reg = 0; reg < 4; ++reg)
                part[reg] += T[mt][reg] * accv[mt][reg];
        #pragma unroll
        for (int reg = 0; reg < 4; ++reg) {
            part[reg] += __shfl_xor(part[reg], 1);
            part[reg] += __shfl_xor(part[reg], 2);
            part[reg] += __shfl_xor(part[reg], 4);
            part[reg] += __shfl_xor(part[reg], 8);
        }
        if (ln == 0) {
            const float wb0 = wgbias[0];
            #pragma unroll
            for (int reg = 0; reg < 4; ++reg) {
                int l = t0 + wave*16 + qd*4 + reg;
                float s = part[reg] + wb0;
                float rr = fmaxf(s, 0.0f);
                GL[bh*1024 + l] = rr*rr + 1e-5f;
            }
        }
    }
    gsync(CNT + 2, 256);

    // =====================================================================
    // P3: gate scan + A_part from in-LDS conv tiles.  Same block mapping
    // as P2, so kts/vts hold exactly rows [t0, t0+64).
    // =====================================================================
    {
        float (*kts)[68] = (float(*)[68])arena;
        float (*vts)[68] = (float(*)[68])(arena + 17408);
        float* wfull = (float*)(arena + 34816);
        float* scanA = (float*)(arena + 38912);
        float* scanB = (float*)(arena + 38928);
        const int bh = blk & 15, it = blk >> 4, t0 = it * 64;

        {
            const float4 g4 = ((const float4*)(GL + bh*1024))[tid];
            float g[4] = {g4.x, g4.y, g4.z, g4.w};
            float p[4];
            p[0]=g[0]; p[1]=p[0]+g[1]; p[2]=p[1]+g[2]; p[3]=p[2]+g[3];
            float xs = p[3];
            #pragma unroll
            for (int off = 1; off < 64; off <<= 1) {
                float t = __shfl_up(xs, off);
                if (lane >= off) xs += t;
            }
            if (lane == 63) scanA[wave] = xs;
            __syncthreads();
            float wb = 0.f;
            #pragma unroll
            for (int wv2 = 0; wv2 < 4; ++wv2) wb += (wv2 < wave) ? scanA[wv2] : 0.f;
            const float base = wb + xs - p[3];
            float r[4], pr[4];
            #pragma unroll
            for (int u = 0; u < 4; ++u) r[u] = 1.0f / (base + p[u] + 1e-5f);
            pr[0]=r[0]; pr[1]=pr[0]+r[1]; pr[2]=pr[1]+r[2]; pr[3]=pr[2]+r[3];
            float y = pr[3];
            #pragma unroll
            for (int off = 1; off < 64; off <<= 1) {
                float t = __shfl_up(y, off);
                if (lane >= off) y += t;
            }
            if (lane == 63) scanB[wave] = y;
            __syncthreads();
            float rb = 0.f, Rtot = 0.f;
            #pragma unroll
            for (int wv2 = 0; wv2 < 4; ++wv2) {
                rb   += (wv2 < wave) ? scanB[wv2] : 0.f;
                Rtot += scanB[wv2];
            }
            const float baser = rb + y - pr[3];
            wfull[tid*4+0] = g[0] * (Rtot - (baser + pr[0]) + r[0]);
            wfull[tid*4+1] = g[1] * (Rtot - (baser + pr[1]) + r[1]);
            wfull[tid*4+2] = g[2] * (Rtot - (baser + pr[2]) + r[2]);
            wfull[tid*4+3] = g[3] * (Rtot - (baser + pr[3]) + r[3]);
        }
        __syncthreads();

        float acc[4][4] = {};
        #pragma unroll 16
        for (int jj = 0; jj < 64; ++jj) {
            float wj = wfull[t0 + jj];
            float4 av = *(const float4*)&vts[jj][ty*4];
            float a[4] = { av.x*wj, av.y*wj, av.z*wj, av.w*wj };
            float4 b4 = *(const float4*)&kts[jj][tx*4];
            float bb[4] = {b4.x, b4.y, b4.z, b4.w};
            #pragma unroll
            for (int ii = 0; ii < 4; ++ii)
                #pragma unroll
                for (int jc = 0; jc < 4; ++jc)
                    acc[ii][jc] += a[ii] * bb[jc];
        }
        float* ap = AP + (size_t)(it*16 + bh) * 4096;
        #pragma unroll
        for (int i = 0; i < 4; ++i) {
            float4 o = { acc[i][0], acc[i][1], acc[i][2], acc[i][3] };
            *(float4*)&ap[(ty*4+i)*64 + tx*4] = o;
        }
    }
    gsync(CNT + 3, 256);

    // =====================================================================
    // P3.5: reduce 16 A-partials -> Afull[bh][4096]
    // =====================================================================
    {
        const int bh = blk >> 4, p = blk & 15;
        int idx = p*256 + tid;
        float s = 0.f;
        #pragma unroll
        for (int sl = 0; sl < 16; ++sl)
            s += AP[(size_t)(sl*16 + bh)*4096 + idx];
        AF[bh*4096 + idx] = s;
    }
    gsync(CNT + 4, 256);

    // =====================================================================
    // P4: ctxt = q @ A, row-normalize, write unit vectors bf16 -> UB.
    // block (lt = blk>>4, bh = blk&15).
    // =====================================================================
    {
        float (*qs)[20]  = (float(*)[20])arena;
        float (*As16)[68] = (float(*)[68])(arena + 5120);
        float (*red)[17] = (float(*)[17])(arena + 9472);
        float* nrm = (float*)(arena + 13824);
        const int l0 = (blk >> 4) * 64;
        const int bh = blk & 15;
        const float* qb = Qb + (size_t)bh * 65536;

        float acc[4][4] = {};
        const float4* q4 = (const float4*)qb;
        for (int d0 = 0; d0 < 64; d0 += 16) {
            {
                int r = tid >> 2, c4 = tid & 3;
                float4 t = q4[(size_t)(l0 + r)*16 + (d0 >> 2) + c4];
                *(float4*)&qs[r][c4*4] = t;
            }
            {
                int r = tid >> 4, c4 = tid & 15;
                float4 t = ((const float4*)AF)[(size_t)bh*1024 + (size_t)(d0 + r)*16 + c4];
                *(float4*)&As16[r][c4*4] = t;
            }
            __syncthreads();
            float qreg[4][16];
            #pragma unroll
            for (int i = 0; i < 4; ++i)
                #pragma unroll
                for (int c = 0; c < 4; ++c) {
                    float4 t = *(const float4*)&qs[ty*4+i][c*4];
                    qreg[i][c*4+0] = t.x; qreg[i][c*4+1] = t.y;
                    qreg[i][c*4+2] = t.z; qreg[i][c*4+3] = t.w;
                }
            #pragma unroll
            for (int dd = 0; dd < 16; ++dd) {
                float4 b4 = *(const float4*)&As16[dd][tx*4];
                float bb[4] = {b4.x, b4.y, b4.z, b4.w};
                #pragma unroll
                for (int ii = 0; ii < 4; ++ii)
                    #pragma unroll
                    for (int jj = 0; jj < 4; ++jj)
                        acc[ii][jj] += qreg[ii][dd] * bb[jj];
            }
            __syncthreads();
        }
        #pragma unroll
        for (int i = 0; i < 4; ++i) {
            red[ty*4+i][tx] = acc[i][0]*acc[i][0] + acc[i][1]*acc[i][1]
                            + acc[i][2]*acc[i][2] + acc[i][3]*acc[i][3];
        }
        __syncthreads();
        if (tid < 64) {
            float s = 0.0f;
            #pragma unroll
            for (int t = 0; t < 16; ++t) s += red[tid][t];
            nrm[tid] = fmaxf(sqrtf(s), 1e-5f);
        }
        __syncthreads();
        const int b = bh >> 3, hd = bh & 7;
        #pragma unroll
        for (int i = 0; i < 4; ++i) {
            int lr = ty*4 + i;
            float inv = 1.0f / nrm[lr];
            ushort4 o;
            o.x = f2bf(acc[i][0]*inv); o.y = f2bf(acc[i][1]*inv);
            o.z = f2bf(acc[i][2]*inv); o.w = f2bf(acc[i][3]*inv);
            *(ushort4*)&UB[(size_t)(b*1024 + l0 + lr)*512 + hd*64 + tx*4] = o;
        }
    }
    gsync(CNT + 5, 256);

    // =====================================================================
    // P5: out = UB @ woT^T + bo.  256 even tiles of 64x64.
    // =====================================================================
    {
        unsigned short* As = (unsigned short*)arena;            // 64*72
        unsigned short* Bs = (unsigned short*)(arena + 9216);
        const int m0 = (blk >> 3) * 64;
        const int n0 = (blk & 7) * 64;

        floatx4 acc[4];
        #pragma unroll
        for (int i = 0; i < 4; ++i) acc[i] = (floatx4){0.f,0.f,0.f,0.f};

        const uint4* Ag = (const uint4*)UB;
        const uint4* Bg = (const uint4*)WOT;
        for (int k0 = 0; k0 < 512; k0 += 64) {
            #pragma unroll
            for (int s = 0; s < 2; ++s) {
                int idx = s*256 + tid;
                int r = idx >> 3, cp = idx & 7;
                *(uint4*)&As[r*72 + cp*8] = Ag[(size_t)(m0 + r)*64 + (k0 >> 3) + cp];
                *(uint4*)&Bs[r*72 + cp*8] = Bg[(size_t)(n0 + r)*64 + (k0 >> 3) + cp];
            }
            __syncthreads();
            short8 af0 = *(const short8*)&As[(wave*16 + ln)*72 + qd*8];
            short8 af1 = *(const short8*)&As[(wave*16 + ln)*72 + 32 + qd*8];
            #pragma unroll
            for (int ni = 0; ni < 4; ++ni) {
                short8 bf0 = *(const short8*)&Bs[(ni*16 + ln)*72 + qd*8];
                short8 bf1 = *(const short8*)&Bs[(ni*16 + ln)*72 + 32 + qd*8];
                acc[ni] = __builtin_amdgcn_mfma_f32_16x16x32_bf16(af0, bf0, acc[ni], 0, 0, 0);
                acc[ni] = __builtin_amdgcn_mfma_f32_16x16x32_bf16(af1, bf1, acc[ni], 0, 0, 0);
            }
            __syncthreads();
        }

        #pragma unroll
        for (int ni = 0; ni < 4; ++ni) {
            int gcol = n0 + ni*16 + ln;
            float bb = bo[gcol];
            #pragma unroll
            for (int reg = 0; reg < 4; ++reg) {
                int row = m0 + wave*16 + qd*4 + reg;
                out[(size_t)row*512 + gcol] = acc[ni][reg] + bb;
            }
        }
    }
}

extern "C" void kernel_launch(void* const* d_in, const int* in_sizes, int n_in,
                              void* d_out, int out_size, void* d_ws, size_t ws_size,
                              hipStream_t stream)
{
    const float* x   = (const float*)d_in[0];
    const float* sb  = (const float*)d_in[1];
    const float* wq  = (const float*)d_in[2];
    const float* bq  = (const float*)d_in[3];
    const float* wk  = (const float*)d_in[4];
    const float* bk  = (const float*)d_in[5];
    const float* wv  = (const float*)d_in[6];
    const float* bv  = (const float*)d_in[7];
    const float* wo  = (const float*)d_in[8];
    const float* bo  = (const float*)d_in[9];
    const float* wg  = (const float*)d_in[10];
    const float* wgb = (const float*)d_in[11];
    float* out = (float*)d_out;
    float* ws  = (float*)d_ws;

    // workspace layout (float offsets); CNT occupies ws[0..15] (64 B)
    unsigned int* CNT = (unsigned int*)ws;
    float* Qb  = ws + 64;                   // 1048576 f32
    float* GL  = Qb + 1048576;              // 16384
    float* AP  = GL + 16384;                // 1048576
    float* AF  = AP + 1048576;              // 65536
    float* fp  = AF + 65536;
    unsigned short* XB  = (unsigned short*)fp;              // 1048576 u16
    unsigned short* WT  = XB  + 1048576;                    // 786432
    unsigned short* WOT = WT  + 786432;                     // 262144
    unsigned short* UB  = WOT + 262144;                     // 1048576
    unsigned short* UB2 = UB  + 1048576;                    // 2097152
    unsigned short* WGB = UB2 + 2097152;                    // 4096

    hipMemsetAsync(CNT, 0, 64, stream);     // zero barrier counters
    k_mega<<<dim3(256), dim3(256), 0, stream>>>(
        x, sb, wq, wk, wv, wo, wg, bq, bk, bv, bo, wgb,
        XB, WT, WOT, WGB, Qb, UB2, GL, AP, AF, UB, out, CNT);
}

// Round 4
// 211.880 us; speedup vs baseline: 1.2477x; 1.2477x over previous
//
#include <hip/hip_runtime.h>
#include <math.h>

// Problem constants: B=2, L=1024, D=512, H=8, h=64, K=H=8, EPS=1e-5
// R4: mega-kernel as R3, but the grid barrier is rebuilt around ONE L2
// writeback per XCD instead of per-block __threadfence pairs (R3 profile:
// 190us with MfmaUtil 1.4% -> ~27us per barrier, dominated by 64 serialized
// buffer_wbl2/buffer_inv L2 tag-walks per XCD per barrier).
// New gsync: all blocks arrive on gcnt (stores already drained to L2 by the
// compiler's waitcnt before s_barrier); the FIRST arriver per XCC_ID becomes
// leader; after gcnt==256 each leader does one release-fence (wbl2) + one
// acquire-fence (inv) and bumps done; everyone proceeds at done==nlead.
// Residency-agnostic: nlead is counted dynamically, so imbalanced or even
// degenerate XCC_ID readings cannot deadlock (failure mode would be a wrong
// result, which the harness detects).
// Phases (math bit-identical to the R1-verified split kernels):
//   P0 prep -> P1 qkv -> P2 conv+gate (kts/vts persist in LDS) -> P3 amat
//   -> P3.5 AP-reduce -> P4 ctxt -> P5 out

typedef __attribute__((ext_vector_type(8))) short short8;
typedef __attribute__((ext_vector_type(4))) float floatx4;

__device__ __forceinline__ unsigned short f2bf(float f) {
    unsigned int u = __float_as_uint(f);
    unsigned int r = (u + 0x7FFFu + ((u >> 16) & 1u)) >> 16;   // RNE
    return (unsigned short)r;
}

// Grid barrier.  slot = 64 zeroed u32: [0..7]=per-XCD arrivals, [16]=nlead,
// [24]=gcnt, [32]=done.  HW_REG_XCC_ID = hwreg 20, offset 0, size 4
// -> getreg imm = ((4-1)<<11) | (0<<6) | 20 = 6164.
__device__ __forceinline__ void gsync(unsigned int* slot) {
    __syncthreads();   // compiler drains vmcnt for ALL waves before s_barrier
    if (threadIdx.x == 0) {
        const unsigned xcd = __builtin_amdgcn_s_getreg(6164) & 7u;
        const unsigned nx = __hip_atomic_fetch_add(&slot[xcd], 1u,
                                __ATOMIC_RELAXED, __HIP_MEMORY_SCOPE_AGENT);
        if (nx == 0u) {   // leader of this XCD
            unsigned t = __hip_atomic_fetch_add(&slot[16], 1u,
                                __ATOMIC_RELAXED, __HIP_MEMORY_SCOPE_AGENT);
            asm volatile("" :: "v"(t));   // nlead-add completes before gcnt-add
        }
        __hip_atomic_fetch_add(&slot[24], 1u,
                               __ATOMIC_RELAXED, __HIP_MEMORY_SCOPE_AGENT);
        while (__hip_atomic_load(&slot[24], __ATOMIC_RELAXED,
                                 __HIP_MEMORY_SCOPE_AGENT) < 256u)
            __builtin_amdgcn_s_sleep(8);
        if (nx == 0u) {
            // one wbl2 per XCD: flushes ALL co-resident blocks' writes
            __builtin_amdgcn_fence(__ATOMIC_RELEASE, "agent");
            __builtin_amdgcn_fence(__ATOMIC_ACQUIRE, "agent");
            __hip_atomic_fetch_add(&slot[32], 1u,
                                   __ATOMIC_RELAXED, __HIP_MEMORY_SCOPE_AGENT);
        }
        const unsigned nl = __hip_atomic_load(&slot[16], __ATOMIC_RELAXED,
                                              __HIP_MEMORY_SCOPE_AGENT);
        while (__hip_atomic_load(&slot[32], __ATOMIC_RELAXED,
                                 __HIP_MEMORY_SCOPE_AGENT) < nl)
            __builtin_amdgcn_s_sleep(8);
    }
    __syncthreads();
    asm volatile("" ::: "memory");
}

__global__ __launch_bounds__(256, 1) void k_mega(
    const float* __restrict__ x, const float* __restrict__ sb,
    const float* __restrict__ wq, const float* __restrict__ wk,
    const float* __restrict__ wv, const float* __restrict__ wo,
    const float* __restrict__ wgw,
    const float* __restrict__ bq, const float* __restrict__ bk,
    const float* __restrict__ bv, const float* __restrict__ bo,
    const float* __restrict__ wgbias,
    unsigned short* __restrict__ XB, unsigned short* __restrict__ WT,
    unsigned short* __restrict__ WOT, unsigned short* __restrict__ WGB,
    float* __restrict__ Qb, unsigned short* __restrict__ UB2,
    float* __restrict__ GL, float* __restrict__ AP,
    float* __restrict__ AF, unsigned short* __restrict__ UB,
    float* __restrict__ out,
    unsigned int* __restrict__ CNT)
{
    const int blk = blockIdx.x;
    const int tid = threadIdx.x;
    const int lane = tid & 63, wave = tid >> 6;
    const int qd = lane >> 4, ln = lane & 15;
    const int tx = tid & 15, ty = tid >> 4;

    __shared__ __align__(16) unsigned char arena[55552];

    // =====================================================================
    // P0: prep.  Each block: 2 castx units, 1 packw unit; blk 0 also wg.
    // =====================================================================
    {
        float (*sf)[65] = (float(*)[65])arena;
        const float4* x4 = (const float4*)x;
        #pragma unroll
        for (int u = 0; u < 2; ++u) {
            int gid = (blk + u*256) * 256 + tid;
            float4 a = x4[gid*2], b = x4[gid*2+1];
            uint4 o;
            o.x = f2bf(a.x) | ((unsigned)f2bf(a.y) << 16);
            o.y = f2bf(a.z) | ((unsigned)f2bf(a.w) << 16);
            o.z = f2bf(b.x) | ((unsigned)f2bf(b.y) << 16);
            o.w = f2bf(b.z) | ((unsigned)f2bf(b.w) << 16);
            ((uint4*)XB)[gid] = o;
        }
        {
            const int t = blk;
            const float* src; unsigned short* dst; int n0p, c0, k0p;
            if (t < 192) {
                int nt = t >> 3, kt = t & 7;
                n0p = nt * 64; k0p = kt * 64;
                int z = n0p >> 9; c0 = n0p & 511;
                src = (z == 0) ? wq : (z == 1) ? wk : wv;
                dst = WT;
            } else {
                int u = t - 192; int nt = u >> 3, kt = u & 7;
                n0p = nt * 64; c0 = n0p; k0p = kt * 64;
                src = wo; dst = WOT;
            }
            const int rr = tid >> 4, c4 = tid & 15;
            #pragma unroll
            for (int g = 0; g < 4; ++g) {
                int r = g*16 + rr;
                float4 v = *(const float4*)&src[(size_t)(k0p + r)*512 + c0 + c4*4];
                sf[r][c4*4+0]=v.x; sf[r][c4*4+1]=v.y; sf[r][c4*4+2]=v.z; sf[r][c4*4+3]=v.w;
            }
            __syncthreads();
            #pragma unroll
            for (int g = 0; g < 4; ++g) {
                int c = g*16 + rr;
                int kk = c4*4;
                ushort4 o;
                o.x = f2bf(sf[kk+0][c]); o.y = f2bf(sf[kk+1][c]);
                o.z = f2bf(sf[kk+2][c]); o.w = f2bf(sf[kk+3][c]);
                *(ushort4*)&dst[(size_t)(n0p + c)*512 + k0p + kk] = o;
            }
        }
        if (blk == 0) {
            const float4* wg4 = (const float4*)wgw;
            for (int i = tid; i < 512; i += 256) {
                float4 a = wg4[i*2], b = wg4[i*2+1];
                uint4 o;
                o.x = f2bf(a.x) | ((unsigned)f2bf(a.y) << 16);
                o.y = f2bf(a.z) | ((unsigned)f2bf(a.w) << 16);
                o.z = f2bf(b.x) | ((unsigned)f2bf(b.y) << 16);
                o.w = f2bf(b.z) | ((unsigned)f2bf(b.w) << 16);
                ((uint4*)WGB)[i] = o;
            }
        }
    }
    gsync(CNT + 0*64);

    // =====================================================================
    // P1: QKV projection.  384 tiles (128m x 64n), blocks 0-127 do two.
    // =====================================================================
    {
        unsigned short* As = (unsigned short*)arena;            // 128*72
        unsigned short* Bs = (unsigned short*)(arena + 18432);  // 64*72
        const int wm = wave * 32;
        const uint4* Ag = (const uint4*)XB;
        const uint4* Bg = (const uint4*)WT;
        for (int t = blk; t < 384; t += 256) {
            const int m0 = (t / 24) * 128;
            const int n0 = (t % 24) * 64;

            floatx4 acc[2][4];
            #pragma unroll
            for (int i = 0; i < 2; ++i)
                #pragma unroll
                for (int j = 0; j < 4; ++j)
                    acc[i][j] = (floatx4){0.f, 0.f, 0.f, 0.f};

            for (int k0 = 0; k0 < 512; k0 += 64) {
                #pragma unroll
                for (int s = 0; s < 4; ++s) {
                    int idx = s*256 + tid;
                    int r = idx >> 3, cp = idx & 7;
                    uint4 va = Ag[(size_t)(m0 + r)*64 + (k0 >> 3) + cp];
                    *(uint4*)&As[r*72 + cp*8] = va;
                }
                #pragma unroll
                for (int s = 0; s < 2; ++s) {
                    int idx = s*256 + tid;
                    int r = idx >> 3, cp = idx & 7;
                    uint4 vb = Bg[(size_t)(n0 + r)*64 + (k0 >> 3) + cp];
                    *(uint4*)&Bs[r*72 + cp*8] = vb;
                }
                __syncthreads();
                short8 af0[2], af1[2], bf0[4], bf1[4];
                #pragma unroll
                for (int i = 0; i < 2; ++i) {
                    af0[i] = *(const short8*)&As[(wm + i*16 + ln)*72 + qd*8];
                    af1[i] = *(const short8*)&As[(wm + i*16 + ln)*72 + 32 + qd*8];
                }
                #pragma unroll
                for (int i = 0; i < 4; ++i) {
                    bf0[i] = *(const short8*)&Bs[(i*16 + ln)*72 + qd*8];
                    bf1[i] = *(const short8*)&Bs[(i*16 + ln)*72 + 32 + qd*8];
                }
                #pragma unroll
                for (int mi = 0; mi < 2; ++mi)
                    #pragma unroll
                    for (int ni = 0; ni < 4; ++ni) {
                        acc[mi][ni] = __builtin_amdgcn_mfma_f32_16x16x32_bf16(
                            af0[mi], bf0[ni], acc[mi][ni], 0, 0, 0);
                        acc[mi][ni] = __builtin_amdgcn_mfma_f32_16x16x32_bf16(
                            af1[mi], bf1[ni], acc[mi][ni], 0, 0, 0);
                    }
                __syncthreads();
            }

            const int z = n0 >> 9;
            if (z == 0) {
                #pragma unroll
                for (int mi = 0; mi < 2; ++mi) {
                    #pragma unroll
                    for (int ni = 0; ni < 4; ++ni) {
                        int c = (n0 + ni*16 + ln) & 511;
                        int head = c >> 6, dd = c & 63;
                        float bb = bq[c];
                        #pragma unroll
                        for (int reg = 0; reg < 4; ++reg) {
                            int row = m0 + wm + mi*16 + qd*4 + reg;
                            int b = row >> 10, l = row & 1023;
                            Qb[(size_t)((b*8 + head)*1024 + l)*64 + dd] =
                                acc[mi][ni][reg] + bb;
                        }
                    }
                }
            } else {
                const float scale = (z == 1) ? 0.125f : 1.0f;
                const float* bias = (z == 1) ? bk : bv;
                unsigned short* dst = UB2 + (size_t)(z-1) * 16 * 64 * 1024;
                #pragma unroll
                for (int mi = 0; mi < 2; ++mi) {
                    #pragma unroll
                    for (int ni = 0; ni < 4; ++ni) {
                        int c = (n0 + ni*16 + ln) & 511;
                        int head = c >> 6, dd = c & 63;
                        float bb = bias[c];
                        int row0 = m0 + wm + mi*16 + qd*4;
                        int b = row0 >> 10, l0 = row0 & 1023;
                        ushort4 o;
                        o.x = f2bf((acc[mi][ni][0] + bb) * scale);
                        o.y = f2bf((acc[mi][ni][1] + bb) * scale);
                        o.z = f2bf((acc[mi][ni][2] + bb) * scale);
                        o.w = f2bf((acc[mi][ni][3] + bb) * scale);
                        *(ushort4*)&dst[((size_t)((b*8 + head)*64) + dd)*1024 + l0] = o;
                    }
                }
            }
        }
    }
    gsync(CNT + 1*64);

    // =====================================================================
    // P2: conv (k AND v) + gate.  block (bh = blk&15, it = blk>>4).
    // Conv outputs stay in LDS (kts/vts) for P3; only gl goes to global.
    // =====================================================================
    {
        float (*kts)[68] = (float(*)[68])arena;
        float (*vts)[68] = (float(*)[68])(arena + 17408);
        unsigned short* revf = (unsigned short*)(arena + 34816);
        unsigned short* Bk = (unsigned short*)(arena + 37120);
        unsigned short* Bv = (unsigned short*)(arena + 46336);
        const int bh = blk & 15, h = bh & 7;
        const int it = blk >> 4, t0 = it * 64;

        for (int i = tid; i < 1152; i += 256) {
            int d = 1087 - i;
            revf[i] = (d >= 0 && d < 1024) ? f2bf(sb[d*8 + h]) : (unsigned short)0;
        }

        const uint4* Bg = (const uint4*)UB2;
        const size_t bk_base = (size_t)bh * 8192;
        const size_t bv_base = (size_t)(16 + bh) * 8192;

        floatx4 acck[4], accv[4];
        #pragma unroll
        for (int i = 0; i < 4; ++i) {
            acck[i] = (floatx4){0.f,0.f,0.f,0.f};
            accv[i] = (floatx4){0.f,0.f,0.f,0.f};
        }

        const int kend = t0 + 64;
        const int arow = 1087 - t0 - (wave*16 + ln);
        for (int k0 = 0; k0 < kend; k0 += 64) {
            #pragma unroll
            for (int s = 0; s < 2; ++s) {
                int idx = s*256 + tid;
                int r = idx >> 3, cp = idx & 7;
                *(uint4*)&Bk[r*72 + cp*8] = Bg[bk_base + (size_t)r*128 + (k0 >> 3) + cp];
                *(uint4*)&Bv[r*72 + cp*8] = Bg[bv_base + (size_t)r*128 + (k0 >> 3) + cp];
            }
            __syncthreads();                   // also covers revf on first iter
            const int ab = arow + k0 + qd*8;
            short8 a0, a1;
            #pragma unroll
            for (int j = 0; j < 8; ++j) {
                a0[j] = (short)revf[ab + j];
                a1[j] = (short)revf[ab + 32 + j];
            }
            #pragma unroll
            for (int ni = 0; ni < 4; ++ni) {
                short8 kb0 = *(const short8*)&Bk[(ni*16 + ln)*72 + qd*8];
                short8 kb1 = *(const short8*)&Bk[(ni*16 + ln)*72 + 32 + qd*8];
                short8 vb0 = *(const short8*)&Bv[(ni*16 + ln)*72 + qd*8];
                short8 vb1 = *(const short8*)&Bv[(ni*16 + ln)*72 + 32 + qd*8];
                acck[ni] = __builtin_amdgcn_mfma_f32_16x16x32_bf16(a0, kb0, acck[ni], 0, 0, 0);
                acck[ni] = __builtin_amdgcn_mfma_f32_16x16x32_bf16(a1, kb1, acck[ni], 0, 0, 0);
                accv[ni] = __builtin_amdgcn_mfma_f32_16x16x32_bf16(a0, vb0, accv[ni], 0, 0, 0);
                accv[ni] = __builtin_amdgcn_mfma_f32_16x16x32_bf16(a1, vb1, accv[ni], 0, 0, 0);
            }
            __syncthreads();
        }

        // epilogue: conv tiles -> LDS (persist), KCb bf16 -> Bk, Wgb -> Bv
        #pragma unroll
        for (int ni = 0; ni < 4; ++ni)
            #pragma unroll
            for (int reg = 0; reg < 4; ++reg) {
                int row = wave*16 + qd*4 + reg;
                kts[row][ni*16 + ln] = acck[ni][reg];
                vts[row][ni*16 + ln] = accv[ni][reg];
                Bk[row*72 + ni*16 + ln] = f2bf(acck[ni][reg]);
            }
        {
            const uint4* Wg = (const uint4*)WGB;
            #pragma unroll
            for (int s = 0; s < 2; ++s) {
                int idx = s*256 + tid;
                int r = idx >> 3, cp = idx & 7;
                *(uint4*)&Bv[r*72 + cp*8] = Wg[r*8 + cp];
            }
        }
        __syncthreads();

        floatx4 T[4];
        #pragma unroll
        for (int mt = 0; mt < 4; ++mt) T[mt] = (floatx4){0.f,0.f,0.f,0.f};
        #pragma unroll
        for (int k0g = 0; k0g < 64; k0g += 32) {
            short8 a = *(const short8*)&Bk[(wave*16 + ln)*72 + k0g + qd*8];
            #pragma unroll
            for (int mt = 0; mt < 4; ++mt) {
                short8 b = *(const short8*)&Bv[(mt*16 + ln)*72 + k0g + qd*8];
                T[mt] = __builtin_amdgcn_mfma_f32_16x16x32_bf16(a, b, T[mt], 0, 0, 0);
            }
        }

        float part[4] = {0.f, 0.f, 0.f, 0.f};
        #pragma unroll
        for (int mt = 0; mt < 4; ++mt)
            #pragma unroll
            for (int reg = 0; reg < 4; ++reg)
                part[reg] += T[mt][reg] * accv[mt][reg];
        #pragma unroll
        for (int reg = 0; reg < 4; ++reg) {
            part[reg] += __shfl_xor(part[reg], 1);
            part[reg] += __shfl_xor(part[reg], 2);
            part[reg] += __shfl_xor(part[reg], 4);
            part[reg] += __shfl_xor(part[reg], 8);
        }
        if (ln == 0) {
            const float wb0 = wgbias[0];
            #pragma unroll
            for (int reg = 0; reg < 4; ++reg) {
                int l = t0 + wave*16 + qd*4 + reg;
                float s = part[reg] + wb0;
                float rr = fmaxf(s, 0.0f);
                GL[bh*1024 + l] = rr*rr + 1e-5f;
            }
        }
    }
    gsync(CNT + 2*64);

    // =====================================================================
    // P3: gate scan + A_part from in-LDS conv tiles.  Same block mapping
    // as P2, so kts/vts hold exactly rows [t0, t0+64).
    // =====================================================================
    {
        float (*kts)[68] = (float(*)[68])arena;
        float (*vts)[68] = (float(*)[68])(arena + 17408);
        float* wfull = (float*)(arena + 34816);
        float* scanA = (float*)(arena + 38912);
        float* scanB = (float*)(arena + 38928);
        const int bh = blk & 15, it = blk >> 4, t0 = it * 64;

        {
            const float4 g4 = ((const float4*)(GL + bh*1024))[tid];
            float g[4] = {g4.x, g4.y, g4.z, g4.w};
            float p[4];
            p[0]=g[0]; p[1]=p[0]+g[1]; p[2]=p[1]+g[2]; p[3]=p[2]+g[3];
            float xs = p[3];
            #pragma unroll
            for (int off = 1; off < 64; off <<= 1) {
                float t = __shfl_up(xs, off);
                if (lane >= off) xs += t;
            }
            if (lane == 63) scanA[wave] = xs;
            __syncthreads();
            float wb = 0.f;
            #pragma unroll
            for (int wv2 = 0; wv2 < 4; ++wv2) wb += (wv2 < wave) ? scanA[wv2] : 0.f;
            const float base = wb + xs - p[3];
            float r[4], pr[4];
            #pragma unroll
            for (int u = 0; u < 4; ++u) r[u] = 1.0f / (base + p[u] + 1e-5f);
            pr[0]=r[0]; pr[1]=pr[0]+r[1]; pr[2]=pr[1]+r[2]; pr[3]=pr[2]+r[3];
            float y = pr[3];
            #pragma unroll
            for (int off = 1; off < 64; off <<= 1) {
                float t = __shfl_up(y, off);
                if (lane >= off) y += t;
            }
            if (lane == 63) scanB[wave] = y;
            __syncthreads();
            float rb = 0.f, Rtot = 0.f;
            #pragma unroll
            for (int wv2 = 0; wv2 < 4; ++wv2) {
                rb   += (wv2 < wave) ? scanB[wv2] : 0.f;
                Rtot += scanB[wv2];
            }
            const float baser = rb + y - pr[3];
            wfull[tid*4+0] = g[0] * (Rtot - (baser + pr[0]) + r[0]);
            wfull[tid*4+1] = g[1] * (Rtot - (baser + pr[1]) + r[1]);
            wfull[tid*4+2] = g[2] * (Rtot - (baser + pr[2]) + r[2]);
            wfull[tid*4+3] = g[3] * (Rtot - (baser + pr[3]) + r[3]);
        }
        __syncthreads();

        float acc[4][4] = {};
        #pragma unroll 16
        for (int jj = 0; jj < 64; ++jj) {
            float wj = wfull[t0 + jj];
            float4 av = *(const float4*)&vts[jj][ty*4];
            float a[4] = { av.x*wj, av.y*wj, av.z*wj, av.w*wj };
            float4 b4 = *(const float4*)&kts[jj][tx*4];
            float bb[4] = {b4.x, b4.y, b4.z, b4.w};
            #pragma unroll
            for (int ii = 0; ii < 4; ++ii)
                #pragma unroll
                for (int jc = 0; jc < 4; ++jc)
                    acc[ii][jc] += a[ii] * bb[jc];
        }
        float* ap = AP + (size_t)(it*16 + bh) * 4096;
        #pragma unroll
        for (int i = 0; i < 4; ++i) {
            float4 o = { acc[i][0], acc[i][1], acc[i][2], acc[i][3] };
            *(float4*)&ap[(ty*4+i)*64 + tx*4] = o;
        }
    }
    gsync(CNT + 3*64);

    // =====================================================================
    // P3.5: reduce 16 A-partials -> Afull[bh][4096]
    // =====================================================================
    {
        const int bh = blk >> 4, p = blk & 15;
        int idx = p*256 + tid;
        float s = 0.f;
        #pragma unroll
        for (int sl = 0; sl < 16; ++sl)
            s += AP[(size_t)(sl*16 + bh)*4096 + idx];
        AF[bh*4096 + idx] = s;
    }
    gsync(CNT + 4*64);

    // =====================================================================
    // P4: ctxt = q @ A, row-normalize, write unit vectors bf16 -> UB.
    // block (lt = blk>>4, bh = blk&15).
    // =====================================================================
    {
        float (*qs)[20]  = (float(*)[20])arena;
        float (*As16)[68] = (float(*)[68])(arena + 5120);
        float (*red)[17] = (float(*)[17])(arena + 9472);
        float* nrm = (float*)(arena + 13824);
        const int l0 = (blk >> 4) * 64;
        const int bh = blk & 15;
        const float* qb = Qb + (size_t)bh * 65536;

        float acc[4][4] = {};
        const float4* q4 = (const float4*)qb;
        for (int d0 = 0; d0 < 64; d0 += 16) {
            {
                int r = tid >> 2, c4 = tid & 3;
                float4 t = q4[(size_t)(l0 + r)*16 + (d0 >> 2) + c4];
                *(float4*)&qs[r][c4*4] = t;
            }
            {
                int r = tid >> 4, c4 = tid & 15;
                float4 t = ((const float4*)AF)[(size_t)bh*1024 + (size_t)(d0 + r)*16 + c4];
                *(float4*)&As16[r][c4*4] = t;
            }
            __syncthreads();
            float qreg[4][16];
            #pragma unroll
            for (int i = 0; i < 4; ++i)
                #pragma unroll
                for (int c = 0; c < 4; ++c) {
                    float4 t = *(const float4*)&qs[ty*4+i][c*4];
                    qreg[i][c*4+0] = t.x; qreg[i][c*4+1] = t.y;
                    qreg[i][c*4+2] = t.z; qreg[i][c*4+3] = t.w;
                }
            #pragma unroll
            for (int dd = 0; dd < 16; ++dd) {
                float4 b4 = *(const float4*)&As16[dd][tx*4];
                float bb[4] = {b4.x, b4.y, b4.z, b4.w};
                #pragma unroll
                for (int ii = 0; ii < 4; ++ii)
                    #pragma unroll
                    for (int jj = 0; jj < 4; ++jj)
                        acc[ii][jj] += qreg[ii][dd] * bb[jj];
            }
            __syncthreads();
        }
        #pragma unroll
        for (int i = 0; i < 4; ++i) {
            red[ty*4+i][tx] = acc[i][0]*acc[i][0] + acc[i][1]*acc[i][1]
                            + acc[i][2]*acc[i][2] + acc[i][3]*acc[i][3];
        }
        __syncthreads();
        if (tid < 64) {
            float s = 0.0f;
            #pragma unroll
            for (int t = 0; t < 16; ++t) s += red[tid][t];
            nrm[tid] = fmaxf(sqrtf(s), 1e-5f);
        }
        __syncthreads();
        const int b = bh >> 3, hd = bh & 7;
        #pragma unroll
        for (int i = 0; i < 4; ++i) {
            int lr = ty*4 + i;
            float inv = 1.0f / nrm[lr];
            ushort4 o;
            o.x = f2bf(acc[i][0]*inv); o.y = f2bf(acc[i][1]*inv);
            o.z = f2bf(acc[i][2]*inv); o.w = f2bf(acc[i][3]*inv);
            *(ushort4*)&UB[(size_t)(b*1024 + l0 + lr)*512 + hd*64 + tx*4] = o;
        }
    }
    gsync(CNT + 5*64);

    // =====================================================================
    // P5: out = UB @ woT^T + bo.  256 even tiles of 64x64.
    // =====================================================================
    {
        unsigned short* As = (unsigned short*)arena;            // 64*72
        unsigned short* Bs = (unsigned short*)(arena + 9216);
        const int m0 = (blk >> 3) * 64;
        const int n0 = (blk & 7) * 64;

        floatx4 acc[4];
        #pragma unroll
        for (int i = 0; i < 4; ++i) acc[i] = (floatx4){0.f,0.f,0.f,0.f};

        const uint4* Ag = (const uint4*)UB;
        const uint4* Bg = (const uint4*)WOT;
        for (int k0 = 0; k0 < 512; k0 += 64) {
            #pragma unroll
            for (int s = 0; s < 2; ++s) {
                int idx = s*256 + tid;
                int r = idx >> 3, cp = idx & 7;
                *(uint4*)&As[r*72 + cp*8] = Ag[(size_t)(m0 + r)*64 + (k0 >> 3) + cp];
                *(uint4*)&Bs[r*72 + cp*8] = Bg[(size_t)(n0 + r)*64 + (k0 >> 3) + cp];
            }
            __syncthreads();
            short8 af0 = *(const short8*)&As[(wave*16 + ln)*72 + qd*8];
            short8 af1 = *(const short8*)&As[(wave*16 + ln)*72 + 32 + qd*8];
            #pragma unroll
            for (int ni = 0; ni < 4; ++ni) {
                short8 bf0 = *(const short8*)&Bs[(ni*16 + ln)*72 + qd*8];
                short8 bf1 = *(const short8*)&Bs[(ni*16 + ln)*72 + 32 + qd*8];
                acc[ni] = __builtin_amdgcn_mfma_f32_16x16x32_bf16(af0, bf0, acc[ni], 0, 0, 0);
                acc[ni] = __builtin_amdgcn_mfma_f32_16x16x32_bf16(af1, bf1, acc[ni], 0, 0, 0);
            }
            __syncthreads();
        }

        #pragma unroll
        for (int ni = 0; ni < 4; ++ni) {
            int gcol = n0 + ni*16 + ln;
            float bb = bo[gcol];
            #pragma unroll
            for (int reg = 0; reg < 4; ++reg) {
                int row = m0 + wave*16 + qd*4 + reg;
                out[(size_t)row*512 + gcol] = acc[ni][reg] + bb;
            }
        }
    }
}

extern "C" void kernel_launch(void* const* d_in, const int* in_sizes, int n_in,
                              void* d_out, int out_size, void* d_ws, size_t ws_size,
                              hipStream_t stream)
{
    const float* x   = (const float*)d_in[0];
    const float* sb  = (const float*)d_in[1];
    const float* wq  = (const float*)d_in[2];
    const float* bq  = (const float*)d_in[3];
    const float* wk  = (const float*)d_in[4];
    const float* bk  = (const float*)d_in[5];
    const float* wv  = (const float*)d_in[6];
    const float* bv  = (const float*)d_in[7];
    const float* wo  = (const float*)d_in[8];
    const float* bo  = (const float*)d_in[9];
    const float* wg  = (const float*)d_in[10];
    const float* wgb = (const float*)d_in[11];
    float* out = (float*)d_out;
    float* ws  = (float*)d_ws;

    // workspace layout (float offsets); CNT occupies ws[0..383] (1536 B,
    // 6 barriers x 64 u32 slots)
    unsigned int* CNT = (unsigned int*)ws;
    float* Qb  = ws + 1024;                 // 1048576 f32
    float* GL  = Qb + 1048576;              // 16384
    float* AP  = GL + 16384;                // 1048576
    float* AF  = AP + 1048576;              // 65536
    float* fp  = AF + 65536;
    unsigned short* XB  = (unsigned short*)fp;              // 1048576 u16
    unsigned short* WT  = XB  + 1048576;                    // 786432
    unsigned short* WOT = WT  + 786432;                     // 262144
    unsigned short* UB  = WOT + 262144;                     // 1048576
    unsigned short* UB2 = UB  + 1048576;                    // 2097152
    unsigned short* WGB = UB2 + 2097152;                    // 4096

    hipMemsetAsync(CNT, 0, 1536, stream);   // zero barrier counters
    k_mega<<<dim3(256), dim3(256), 0, stream>>>(
        x, sb, wq, wk, wv, wo, wg, bq, bk, bv, bo, wgb,
        XB, WT, WOT, WGB, Qb, UB2, GL, AP, AF, UB, out, CNT);
}

// Round 6
// 174.534 us; speedup vs baseline: 1.5146x; 1.2140x over previous
//
#include <hip/hip_runtime.h>
#include <math.h>

// Problem constants: B=2, L=1024, D=512, H=8, h=64, K=H=8, EPS=1e-5
// R6: same as R5 (store-time device coherence via sc0 sc1 + fence-free grid
// barrier) but inline-asm operands use ext_vector types (clang cannot put
// HIP's struct uint4/float4 into "v" tuple constraints -> R5 compile fail).
// Phases (math bit-identical to R4 / the R1-verified split kernels):
//   P0 prep -> P1 qkv -> P2 conv+gate (kts/vts persist in LDS) -> P3 amat
//   -> P3.5 AP-reduce -> P4 ctxt -> P5 out

typedef __attribute__((ext_vector_type(8))) short short8;
typedef __attribute__((ext_vector_type(4))) float floatx4;
typedef __attribute__((ext_vector_type(2))) unsigned int uintx2;
typedef __attribute__((ext_vector_type(4))) unsigned int uintx4;

__device__ __forceinline__ unsigned short f2bf(float f) {
    unsigned int u = __float_as_uint(f);
    unsigned int r = (u + 0x7FFFu + ((u >> 16) & 1u)) >> 16;   // RNE
    return (unsigned short)r;
}

// Device-coherent (cross-XCD visible) stores: sc0 sc1 write through to the
// coherence point, so no L2 writeback is needed at the grid barrier.
__device__ __forceinline__ void stg_sc1(void* p, float v) {
    asm volatile("global_store_dword %0, %1, off sc0 sc1"
                 :: "v"(p), "v"(v) : "memory");
}
__device__ __forceinline__ void stg_sc2(void* p, uintx2 v) {
    asm volatile("global_store_dwordx2 %0, %1, off sc0 sc1"
                 :: "v"(p), "v"(v) : "memory");
}
__device__ __forceinline__ void stg_sc4(void* p, uintx4 v) {
    asm volatile("global_store_dwordx4 %0, %1, off sc0 sc1"
                 :: "v"(p), "v"(v) : "memory");
}
__device__ __forceinline__ void stg_sc4f(void* p, floatx4 v) {
    asm volatile("global_store_dwordx4 %0, %1, off sc0 sc1"
                 :: "v"(p), "v"(v) : "memory");
}

// Fence-free grid barrier: drain this wave's stores (sc1 stores are at the
// coherence point once vmcnt retires), block-barrier, single arrival atomic.
__device__ __forceinline__ void gsync(unsigned int* cnt) {
    asm volatile("s_waitcnt vmcnt(0)" ::: "memory");
    __syncthreads();
    if (threadIdx.x == 0) {
        __hip_atomic_fetch_add(cnt, 1u, __ATOMIC_RELAXED,
                               __HIP_MEMORY_SCOPE_AGENT);
        while (__hip_atomic_load(cnt, __ATOMIC_RELAXED,
                                 __HIP_MEMORY_SCOPE_AGENT) < 256u)
            __builtin_amdgcn_s_sleep(8);
    }
    __syncthreads();
    asm volatile("" ::: "memory");
}

__global__ __launch_bounds__(256, 1) void k_mega(
    const float* __restrict__ x, const float* __restrict__ sb,
    const float* __restrict__ wq, const float* __restrict__ wk,
    const float* __restrict__ wv, const float* __restrict__ wo,
    const float* __restrict__ wgw,
    const float* __restrict__ bq, const float* __restrict__ bk,
    const float* __restrict__ bv, const float* __restrict__ bo,
    const float* __restrict__ wgbias,
    unsigned short* __restrict__ XB, unsigned short* __restrict__ WT,
    unsigned short* __restrict__ WOT, unsigned short* __restrict__ WGB,
    float* __restrict__ Qb, unsigned short* __restrict__ UB2,
    float* __restrict__ GL, float* __restrict__ AP,
    float* __restrict__ AF, unsigned short* __restrict__ UB,
    float* __restrict__ out,
    unsigned int* __restrict__ CNT)
{
    const int blk = blockIdx.x;
    const int tid = threadIdx.x;
    const int lane = tid & 63, wave = tid >> 6;
    const int qd = lane >> 4, ln = lane & 15;
    const int tx = tid & 15, ty = tid >> 4;

    __shared__ __align__(16) unsigned char arena[55552];

    // =====================================================================
    // P0: prep.  Each block: 2 castx units, 1 packw unit; blk 0 also wg.
    // =====================================================================
    {
        float (*sf)[65] = (float(*)[65])arena;
        const float4* x4 = (const float4*)x;
        #pragma unroll
        for (int u = 0; u < 2; ++u) {
            int gid = (blk + u*256) * 256 + tid;
            float4 a = x4[gid*2], b = x4[gid*2+1];
            uintx4 o;
            o.x = f2bf(a.x) | ((unsigned)f2bf(a.y) << 16);
            o.y = f2bf(a.z) | ((unsigned)f2bf(a.w) << 16);
            o.z = f2bf(b.x) | ((unsigned)f2bf(b.y) << 16);
            o.w = f2bf(b.z) | ((unsigned)f2bf(b.w) << 16);
            stg_sc4((void*)(XB + (size_t)gid*8), o);
        }
        {
            const int t = blk;
            const float* src; unsigned short* dst; int n0p, c0, k0p;
            if (t < 192) {
                int nt = t >> 3, kt = t & 7;
                n0p = nt * 64; k0p = kt * 64;
                int z = n0p >> 9; c0 = n0p & 511;
                src = (z == 0) ? wq : (z == 1) ? wk : wv;
                dst = WT;
            } else {
                int u = t - 192; int nt = u >> 3, kt = u & 7;
                n0p = nt * 64; c0 = n0p; k0p = kt * 64;
                src = wo; dst = WOT;
            }
            const int rr = tid >> 4, c4 = tid & 15;
            #pragma unroll
            for (int g = 0; g < 4; ++g) {
                int r = g*16 + rr;
                float4 v = *(const float4*)&src[(size_t)(k0p + r)*512 + c0 + c4*4];
                sf[r][c4*4+0]=v.x; sf[r][c4*4+1]=v.y; sf[r][c4*4+2]=v.z; sf[r][c4*4+3]=v.w;
            }
            __syncthreads();
            #pragma unroll
            for (int g = 0; g < 4; ++g) {
                int c = g*16 + rr;
                int kk = c4*4;
                uintx2 o;
                o.x = f2bf(sf[kk+0][c]) | ((unsigned)f2bf(sf[kk+1][c]) << 16);
                o.y = f2bf(sf[kk+2][c]) | ((unsigned)f2bf(sf[kk+3][c]) << 16);
                stg_sc2((void*)&dst[(size_t)(n0p + c)*512 + k0p + kk], o);
            }
        }
        if (blk == 0) {
            const float4* wg4 = (const float4*)wgw;
            for (int i = tid; i < 512; i += 256) {
                float4 a = wg4[i*2], b = wg4[i*2+1];
                uintx4 o;
                o.x = f2bf(a.x) | ((unsigned)f2bf(a.y) << 16);
                o.y = f2bf(a.z) | ((unsigned)f2bf(a.w) << 16);
                o.z = f2bf(b.x) | ((unsigned)f2bf(b.y) << 16);
                o.w = f2bf(b.z) | ((unsigned)f2bf(b.w) << 16);
                stg_sc4((void*)(WGB + (size_t)i*8), o);
            }
        }
    }
    gsync(CNT + 0*64);

    // =====================================================================
    // P1: QKV projection.  384 tiles (128m x 64n), blocks 0-127 do two.
    // =====================================================================
    {
        unsigned short* As = (unsigned short*)arena;            // 128*72
        unsigned short* Bs = (unsigned short*)(arena + 18432);  // 64*72
        const int wm = wave * 32;
        const uint4* Ag = (const uint4*)XB;
        const uint4* Bg = (const uint4*)WT;
        for (int t = blk; t < 384; t += 256) {
            const int m0 = (t / 24) * 128;
            const int n0 = (t % 24) * 64;

            floatx4 acc[2][4];
            #pragma unroll
            for (int i = 0; i < 2; ++i)
                #pragma unroll
                for (int j = 0; j < 4; ++j)
                    acc[i][j] = (floatx4){0.f, 0.f, 0.f, 0.f};

            for (int k0 = 0; k0 < 512; k0 += 64) {
                #pragma unroll
                for (int s = 0; s < 4; ++s) {
                    int idx = s*256 + tid;
                    int r = idx >> 3, cp = idx & 7;
                    uint4 va = Ag[(size_t)(m0 + r)*64 + (k0 >> 3) + cp];
                    *(uint4*)&As[r*72 + cp*8] = va;
                }
                #pragma unroll
                for (int s = 0; s < 2; ++s) {
                    int idx = s*256 + tid;
                    int r = idx >> 3, cp = idx & 7;
                    uint4 vb = Bg[(size_t)(n0 + r)*64 + (k0 >> 3) + cp];
                    *(uint4*)&Bs[r*72 + cp*8] = vb;
                }
                __syncthreads();
                short8 af0[2], af1[2], bf0[4], bf1[4];
                #pragma unroll
                for (int i = 0; i < 2; ++i) {
                    af0[i] = *(const short8*)&As[(wm + i*16 + ln)*72 + qd*8];
                    af1[i] = *(const short8*)&As[(wm + i*16 + ln)*72 + 32 + qd*8];
                }
                #pragma unroll
                for (int i = 0; i < 4; ++i) {
                    bf0[i] = *(const short8*)&Bs[(i*16 + ln)*72 + qd*8];
                    bf1[i] = *(const short8*)&Bs[(i*16 + ln)*72 + 32 + qd*8];
                }
                #pragma unroll
                for (int mi = 0; mi < 2; ++mi)
                    #pragma unroll
                    for (int ni = 0; ni < 4; ++ni) {
                        acc[mi][ni] = __builtin_amdgcn_mfma_f32_16x16x32_bf16(
                            af0[mi], bf0[ni], acc[mi][ni], 0, 0, 0);
                        acc[mi][ni] = __builtin_amdgcn_mfma_f32_16x16x32_bf16(
                            af1[mi], bf1[ni], acc[mi][ni], 0, 0, 0);
                    }
                __syncthreads();
            }

            const int z = n0 >> 9;
            if (z == 0) {
                #pragma unroll
                for (int mi = 0; mi < 2; ++mi) {
                    #pragma unroll
                    for (int ni = 0; ni < 4; ++ni) {
                        int c = (n0 + ni*16 + ln) & 511;
                        int head = c >> 6, dd = c & 63;
                        float bb = bq[c];
                        #pragma unroll
                        for (int reg = 0; reg < 4; ++reg) {
                            int row = m0 + wm + mi*16 + qd*4 + reg;
                            int b = row >> 10, l = row & 1023;
                            stg_sc1((void*)&Qb[(size_t)((b*8 + head)*1024 + l)*64 + dd],
                                    acc[mi][ni][reg] + bb);
                        }
                    }
                }
            } else {
                const float scale = (z == 1) ? 0.125f : 1.0f;
                const float* bias = (z == 1) ? bk : bv;
                unsigned short* dst = UB2 + (size_t)(z-1) * 16 * 64 * 1024;
                #pragma unroll
                for (int mi = 0; mi < 2; ++mi) {
                    #pragma unroll
                    for (int ni = 0; ni < 4; ++ni) {
                        int c = (n0 + ni*16 + ln) & 511;
                        int head = c >> 6, dd = c & 63;
                        float bb = bias[c];
                        int row0 = m0 + wm + mi*16 + qd*4;
                        int b = row0 >> 10, l0 = row0 & 1023;
                        uintx2 o;
                        o.x = f2bf((acc[mi][ni][0] + bb) * scale)
                            | ((unsigned)f2bf((acc[mi][ni][1] + bb) * scale) << 16);
                        o.y = f2bf((acc[mi][ni][2] + bb) * scale)
                            | ((unsigned)f2bf((acc[mi][ni][3] + bb) * scale) << 16);
                        stg_sc2((void*)&dst[((size_t)((b*8 + head)*64) + dd)*1024 + l0], o);
                    }
                }
            }
        }
    }
    gsync(CNT + 1*64);

    // =====================================================================
    // P2: conv (k AND v) + gate.  block (bh = blk&15, it = blk>>4).
    // Conv outputs stay in LDS (kts/vts) for P3; only gl goes to global.
    // =====================================================================
    {
        float (*kts)[68] = (float(*)[68])arena;
        float (*vts)[68] = (float(*)[68])(arena + 17408);
        unsigned short* revf = (unsigned short*)(arena + 34816);
        unsigned short* Bk = (unsigned short*)(arena + 37120);
        unsigned short* Bv = (unsigned short*)(arena + 46336);
        const int bh = blk & 15, h = bh & 7;
        const int it = blk >> 4, t0 = it * 64;

        for (int i = tid; i < 1152; i += 256) {
            int d = 1087 - i;
            revf[i] = (d >= 0 && d < 1024) ? f2bf(sb[d*8 + h]) : (unsigned short)0;
        }

        const uint4* Bg = (const uint4*)UB2;
        const size_t bk_base = (size_t)bh * 8192;
        const size_t bv_base = (size_t)(16 + bh) * 8192;

        floatx4 acck[4], accv[4];
        #pragma unroll
        for (int i = 0; i < 4; ++i) {
            acck[i] = (floatx4){0.f,0.f,0.f,0.f};
            accv[i] = (floatx4){0.f,0.f,0.f,0.f};
        }

        const int kend = t0 + 64;
        const int arow = 1087 - t0 - (wave*16 + ln);
        for (int k0 = 0; k0 < kend; k0 += 64) {
            #pragma unroll
            for (int s = 0; s < 2; ++s) {
                int idx = s*256 + tid;
                int r = idx >> 3, cp = idx & 7;
                *(uint4*)&Bk[r*72 + cp*8] = Bg[bk_base + (size_t)r*128 + (k0 >> 3) + cp];
                *(uint4*)&Bv[r*72 + cp*8] = Bg[bv_base + (size_t)r*128 + (k0 >> 3) + cp];
            }
            __syncthreads();                   // also covers revf on first iter
            const int ab = arow + k0 + qd*8;
            short8 a0, a1;
            #pragma unroll
            for (int j = 0; j < 8; ++j) {
                a0[j] = (short)revf[ab + j];
                a1[j] = (short)revf[ab + 32 + j];
            }
            #pragma unroll
            for (int ni = 0; ni < 4; ++ni) {
                short8 kb0 = *(const short8*)&Bk[(ni*16 + ln)*72 + qd*8];
                short8 kb1 = *(const short8*)&Bk[(ni*16 + ln)*72 + 32 + qd*8];
                short8 vb0 = *(const short8*)&Bv[(ni*16 + ln)*72 + qd*8];
                short8 vb1 = *(const short8*)&Bv[(ni*16 + ln)*72 + 32 + qd*8];
                acck[ni] = __builtin_amdgcn_mfma_f32_16x16x32_bf16(a0, kb0, acck[ni], 0, 0, 0);
                acck[ni] = __builtin_amdgcn_mfma_f32_16x16x32_bf16(a1, kb1, acck[ni], 0, 0, 0);
                accv[ni] = __builtin_amdgcn_mfma_f32_16x16x32_bf16(a0, vb0, accv[ni], 0, 0, 0);
                accv[ni] = __builtin_amdgcn_mfma_f32_16x16x32_bf16(a1, vb1, accv[ni], 0, 0, 0);
            }
            __syncthreads();
        }

        // epilogue: conv tiles -> LDS (persist), KCb bf16 -> Bk, Wgb -> Bv
        #pragma unroll
        for (int ni = 0; ni < 4; ++ni)
            #pragma unroll
            for (int reg = 0; reg < 4; ++reg) {
                int row = wave*16 + qd*4 + reg;
                kts[row][ni*16 + ln] = acck[ni][reg];
                vts[row][ni*16 + ln] = accv[ni][reg];
                Bk[row*72 + ni*16 + ln] = f2bf(acck[ni][reg]);
            }
        {
            const uint4* Wg = (const uint4*)WGB;
            #pragma unroll
            for (int s = 0; s < 2; ++s) {
                int idx = s*256 + tid;
                int r = idx >> 3, cp = idx & 7;
                *(uint4*)&Bv[r*72 + cp*8] = Wg[r*8 + cp];
            }
        }
        __syncthreads();

        floatx4 T[4];
        #pragma unroll
        for (int mt = 0; mt < 4; ++mt) T[mt] = (floatx4){0.f,0.f,0.f,0.f};
        #pragma unroll
        for (int k0g = 0; k0g < 64; k0g += 32) {
            short8 a = *(const short8*)&Bk[(wave*16 + ln)*72 + k0g + qd*8];
            #pragma unroll
            for (int mt = 0; mt < 4; ++mt) {
                short8 b = *(const short8*)&Bv[(mt*16 + ln)*72 + k0g + qd*8];
                T[mt] = __builtin_amdgcn_mfma_f32_16x16x32_bf16(a, b, T[mt], 0, 0, 0);
            }
        }

        float part[4] = {0.f, 0.f, 0.f, 0.f};
        #pragma unroll
        for (int mt = 0; mt < 4; ++mt)
            #pragma unroll
            for (int reg = 0; reg < 4; ++reg)
                part[reg] += T[mt][reg] * accv[mt][reg];
        #pragma unroll
        for (int reg = 0; reg < 4; ++reg) {
            part[reg] += __shfl_xor(part[reg], 1);
            part[reg] += __shfl_xor(part[reg], 2);
            part[reg] += __shfl_xor(part[reg], 4);
            part[reg] += __shfl_xor(part[reg], 8);
        }
        if (ln == 0) {
            const float wb0 = wgbias[0];
            #pragma unroll
            for (int reg = 0; reg < 4; ++reg) {
                int l = t0 + wave*16 + qd*4 + reg;
                float s = part[reg] + wb0;
                float rr = fmaxf(s, 0.0f);
                stg_sc1((void*)&GL[bh*1024 + l], rr*rr + 1e-5f);
            }
        }
    }
    gsync(CNT + 2*64);

    // =====================================================================
    // P3: gate scan + A_part from in-LDS conv tiles.  Same block mapping
    // as P2, so kts/vts hold exactly rows [t0, t0+64).
    // =====================================================================
    {
        float (*kts)[68] = (float(*)[68])arena;
        float (*vts)[68] = (float(*)[68])(arena + 17408);
        float* wfull = (float*)(arena + 34816);
        float* scanA = (float*)(arena + 38912);
        float* scanB = (float*)(arena + 38928);
        const int bh = blk & 15, it = blk >> 4, t0 = it * 64;

        {
            const float4 g4 = ((const float4*)(GL + bh*1024))[tid];
            float g[4] = {g4.x, g4.y, g4.z, g4.w};
            float p[4];
            p[0]=g[0]; p[1]=p[0]+g[1]; p[2]=p[1]+g[2]; p[3]=p[2]+g[3];
            float xs = p[3];
            #pragma unroll
            for (int off = 1; off < 64; off <<= 1) {
                float t = __shfl_up(xs, off);
                if (lane >= off) xs += t;
            }
            if (lane == 63) scanA[wave] = xs;
            __syncthreads();
            float wb = 0.f;
            #pragma unroll
            for (int wv2 = 0; wv2 < 4; ++wv2) wb += (wv2 < wave) ? scanA[wv2] : 0.f;
            const float base = wb + xs - p[3];
            float r[4], pr[4];
            #pragma unroll
            for (int u = 0; u < 4; ++u) r[u] = 1.0f / (base + p[u] + 1e-5f);
            pr[0]=r[0]; pr[1]=pr[0]+r[1]; pr[2]=pr[1]+r[2]; pr[3]=pr[2]+r[3];
            float y = pr[3];
            #pragma unroll
            for (int off = 1; off < 64; off <<= 1) {
                float t = __shfl_up(y, off);
                if (lane >= off) y += t;
            }
            if (lane == 63) scanB[wave] = y;
            __syncthreads();
            float rb = 0.f, Rtot = 0.f;
            #pragma unroll
            for (int wv2 = 0; wv2 < 4; ++wv2) {
                rb   += (wv2 < wave) ? scanB[wv2] : 0.f;
                Rtot += scanB[wv2];
            }
            const float baser = rb + y - pr[3];
            wfull[tid*4+0] = g[0] * (Rtot - (baser + pr[0]) + r[0]);
            wfull[tid*4+1] = g[1] * (Rtot - (baser + pr[1]) + r[1]);
            wfull[tid*4+2] = g[2] * (Rtot - (baser + pr[2]) + r[2]);
            wfull[tid*4+3] = g[3] * (Rtot - (baser + pr[3]) + r[3]);
        }
        __syncthreads();

        float acc[4][4] = {};
        #pragma unroll 16
        for (int jj = 0; jj < 64; ++jj) {
            float wj = wfull[t0 + jj];
            float4 av = *(const float4*)&vts[jj][ty*4];
            float a[4] = { av.x*wj, av.y*wj, av.z*wj, av.w*wj };
            float4 b4 = *(const float4*)&kts[jj][tx*4];
            float bb[4] = {b4.x, b4.y, b4.z, b4.w};
            #pragma unroll
            for (int ii = 0; ii < 4; ++ii)
                #pragma unroll
                for (int jc = 0; jc < 4; ++jc)
                    acc[ii][jc] += a[ii] * bb[jc];
        }
        float* ap = AP + (size_t)(it*16 + bh) * 4096;
        #pragma unroll
        for (int i = 0; i < 4; ++i) {
            floatx4 o = { acc[i][0], acc[i][1], acc[i][2], acc[i][3] };
            stg_sc4f((void*)&ap[(ty*4+i)*64 + tx*4], o);
        }
    }
    gsync(CNT + 3*64);

    // =====================================================================
    // P3.5: reduce 16 A-partials -> Afull[bh][4096]
    // =====================================================================
    {
        const int bh = blk >> 4, p = blk & 15;
        int idx = p*256 + tid;
        float s = 0.f;
        #pragma unroll
        for (int sl = 0; sl < 16; ++sl)
            s += AP[(size_t)(sl*16 + bh)*4096 + idx];
        stg_sc1((void*)&AF[bh*4096 + idx], s);
    }
    gsync(CNT + 4*64);

    // =====================================================================
    // P4: ctxt = q @ A, row-normalize, write unit vectors bf16 -> UB.
    // block (lt = blk>>4, bh = blk&15).
    // =====================================================================
    {
        float (*qs)[20]  = (float(*)[20])arena;
        float (*As16)[68] = (float(*)[68])(arena + 5120);
        float (*red)[17] = (float(*)[17])(arena + 9472);
        float* nrm = (float*)(arena + 13824);
        const int l0 = (blk >> 4) * 64;
        const int bh = blk & 15;
        const float* qb = Qb + (size_t)bh * 65536;

        float acc[4][4] = {};
        const float4* q4 = (const float4*)qb;
        for (int d0 = 0; d0 < 64; d0 += 16) {
            {
                int r = tid >> 2, c4 = tid & 3;
                float4 t = q4[(size_t)(l0 + r)*16 + (d0 >> 2) + c4];
                *(float4*)&qs[r][c4*4] = t;
            }
            {
                int r = tid >> 4, c4 = tid & 15;
                float4 t = ((const float4*)AF)[(size_t)bh*1024 + (size_t)(d0 + r)*16 + c4];
                *(float4*)&As16[r][c4*4] = t;
            }
            __syncthreads();
            float qreg[4][16];
            #pragma unroll
            for (int i = 0; i < 4; ++i)
                #pragma unroll
                for (int c = 0; c < 4; ++c) {
                    float4 t = *(const float4*)&qs[ty*4+i][c*4];
                    qreg[i][c*4+0] = t.x; qreg[i][c*4+1] = t.y;
                    qreg[i][c*4+2] = t.z; qreg[i][c*4+3] = t.w;
                }
            #pragma unroll
            for (int dd = 0; dd < 16; ++dd) {
                float4 b4 = *(const float4*)&As16[dd][tx*4];
                float bb[4] = {b4.x, b4.y, b4.z, b4.w};
                #pragma unroll
                for (int ii = 0; ii < 4; ++ii)
                    #pragma unroll
                    for (int jj = 0; jj < 4; ++jj)
                        acc[ii][jj] += qreg[ii][dd] * bb[jj];
            }
            __syncthreads();
        }
        #pragma unroll
        for (int i = 0; i < 4; ++i) {
            red[ty*4+i][tx] = acc[i][0]*acc[i][0] + acc[i][1]*acc[i][1]
                            + acc[i][2]*acc[i][2] + acc[i][3]*acc[i][3];
        }
        __syncthreads();
        if (tid < 64) {
            float s = 0.0f;
            #pragma unroll
            for (int t = 0; t < 16; ++t) s += red[tid][t];
            nrm[tid] = fmaxf(sqrtf(s), 1e-5f);
        }
        __syncthreads();
        const int b = bh >> 3, hd = bh & 7;
        #pragma unroll
        for (int i = 0; i < 4; ++i) {
            int lr = ty*4 + i;
            float inv = 1.0f / nrm[lr];
            uintx2 o;
            o.x = f2bf(acc[i][0]*inv) | ((unsigned)f2bf(acc[i][1]*inv) << 16);
            o.y = f2bf(acc[i][2]*inv) | ((unsigned)f2bf(acc[i][3]*inv) << 16);
            stg_sc2((void*)&UB[(size_t)(b*1024 + l0 + lr)*512 + hd*64 + tx*4], o);
        }
    }
    gsync(CNT + 5*64);

    // =====================================================================
    // P5: out = UB @ woT^T + bo.  256 even tiles of 64x64.
    // =====================================================================
    {
        unsigned short* As = (unsigned short*)arena;            // 64*72
        unsigned short* Bs = (unsigned short*)(arena + 9216);
        const int m0 = (blk >> 3) * 64;
        const int n0 = (blk & 7) * 64;

        floatx4 acc[4];
        #pragma unroll
        for (int i = 0; i < 4; ++i) acc[i] = (floatx4){0.f,0.f,0.f,0.f};

        const uint4* Ag = (const uint4*)UB;
        const uint4* Bg = (const uint4*)WOT;
        for (int k0 = 0; k0 < 512; k0 += 64) {
            #pragma unroll
            for (int s = 0; s < 2; ++s) {
                int idx = s*256 + tid;
                int r = idx >> 3, cp = idx & 7;
                *(uint4*)&As[r*72 + cp*8] = Ag[(size_t)(m0 + r)*64 + (k0 >> 3) + cp];
                *(uint4*)&Bs[r*72 + cp*8] = Bg[(size_t)(n0 + r)*64 + (k0 >> 3) + cp];
            }
            __syncthreads();
            short8 af0 = *(const short8*)&As[(wave*16 + ln)*72 + qd*8];
            short8 af1 = *(const short8*)&As[(wave*16 + ln)*72 + 32 + qd*8];
            #pragma unroll
            for (int ni = 0; ni < 4; ++ni) {
                short8 bf0 = *(const short8*)&Bs[(ni*16 + ln)*72 + qd*8];
                short8 bf1 = *(const short8*)&Bs[(ni*16 + ln)*72 + 32 + qd*8];
                acc[ni] = __builtin_amdgcn_mfma_f32_16x16x32_bf16(af0, bf0, acc[ni], 0, 0, 0);
                acc[ni] = __builtin_amdgcn_mfma_f32_16x16x32_bf16(af1, bf1, acc[ni], 0, 0, 0);
            }
            __syncthreads();
        }

        #pragma unroll
        for (int ni = 0; ni < 4; ++ni) {
            int gcol = n0 + ni*16 + ln;
            float bb = bo[gcol];
            #pragma unroll
            for (int reg = 0; reg < 4; ++reg) {
                int row = m0 + wave*16 + qd*4 + reg;
                out[(size_t)row*512 + gcol] = acc[ni][reg] + bb;
            }
        }
    }
}

extern "C" void kernel_launch(void* const* d_in, const int* in_sizes, int n_in,
                              void* d_out, int out_size, void* d_ws, size_t ws_size,
                              hipStream_t stream)
{
    const float* x   = (const float*)d_in[0];
    const float* sb  = (const float*)d_in[1];
    const float* wq  = (const float*)d_in[2];
    const float* bq  = (const float*)d_in[3];
    const float* wk  = (const float*)d_in[4];
    const float* bk  = (const float*)d_in[5];
    const float* wv  = (const float*)d_in[6];
    const float* bv  = (const float*)d_in[7];
    const float* wo  = (const float*)d_in[8];
    const float* bo  = (const float*)d_in[9];
    const float* wg  = (const float*)d_in[10];
    const float* wgb = (const float*)d_in[11];
    float* out = (float*)d_out;
    float* ws  = (float*)d_ws;

    // workspace layout (float offsets); CNT occupies ws[0..383] (1536 B,
    // 6 barriers x 64 u32 slots)
    unsigned int* CNT = (unsigned int*)ws;
    float* Qb  = ws + 1024;                 // 1048576 f32
    float* GL  = Qb + 1048576;              // 16384
    float* AP  = GL + 16384;                // 1048576
    float* AF  = AP + 1048576;              // 65536
    float* fp  = AF + 65536;
    unsigned short* XB  = (unsigned short*)fp;              // 1048576 u16
    unsigned short* WT  = XB  + 1048576;                    // 786432
    unsigned short* WOT = WT  + 786432;                     // 262144
    unsigned short* UB  = WOT + 262144;                     // 1048576
    unsigned short* UB2 = UB  + 1048576;                    // 2097152
    unsigned short* WGB = UB2 + 2097152;                    // 4096

    hipMemsetAsync(CNT, 0, 1536, stream);   // zero barrier counters
    k_mega<<<dim3(256), dim3(256), 0, stream>>>(
        x, sb, wq, wk, wv, wo, wg, bq, bk, bv, bo, wgb,
        XB, WT, WOT, WGB, Qb, UB2, GL, AP, AF, UB, out, CNT);
}